// Round 14
// baseline (775.817 us; speedup 1.0000x reference)
//
#include <hip/hip_runtime.h>
#include <cstdint>

// Model dims (fixed): L=128, B=64, DM=1024, H=256, F=512, HID=256, MEM=768,
// N=B*L=8192, NC=6, R=8, NB=30, WIN=10

typedef __attribute__((ext_vector_type(8))) short bf16x8;
typedef __attribute__((ext_vector_type(4))) float f32x4;

__device__ __forceinline__ void gload_lds16(const void* g, void* l) {
  __builtin_amdgcn_global_load_lds(
      (const __attribute__((address_space(1))) void*)g,
      (__attribute__((address_space(3))) void*)l, 16, 0, 0);
}

// ---------------------------------------------------------------------------
// bf16 NT MFMA GEMM (proven): 128x128x32 tile, 4 waves, global_load_lds.
// A row stride lda, C row stride ldc (B row stride == K). Batched via z.
// ---------------------------------------------------------------------------
template<bool HASBIAS, bool ACCUM, bool RELU, bool OUTBF>
__global__ __launch_bounds__(256) void gemm_bf16_nt(
    const ushort* __restrict__ A, const ushort* __restrict__ Bt,
    const float* __restrict__ bias, void* __restrict__ Cv,
    int M, int N, int K, long lda, long ldc,
    long sA, long sB, long sC, long sBias)
{
  const int bz = blockIdx.z;
  A += (long)bz * sA;
  Bt += (long)bz * sB;
  if (HASBIAS) bias += (long)bz * sBias;
  float*  Cf = OUTBF ? nullptr : ((float*)Cv + (long)bz * sC);
  ushort* Cb = OUTBF ? ((ushort*)Cv + (long)bz * sC) : nullptr;

  const int bn = blockIdx.x * 128, bm = blockIdx.y * 128;

  __shared__ ushort As[128][32];
  __shared__ ushort Bs[128][32];

  const int tid = threadIdx.x;
  const int wave = tid >> 6, lane = tid & 63;
  const int wm = (wave >> 1) * 64, wn = (wave & 1) * 64;
  const int fr = lane & 15;
  const int fk = (lane >> 4) * 8;

  f32x4 acc[4][4];
#pragma unroll
  for (int i = 0; i < 4; ++i)
#pragma unroll
    for (int j = 0; j < 4; ++j) acc[i][j] = (f32x4){0.f, 0.f, 0.f, 0.f};

  const int f0 = wave * 2 * 64 + lane;
  const int f1 = f0 + 64;
  const int r0 = f0 >> 2, c0 = (f0 & 3) * 8;
  const int r1 = f1 >> 2, c1 = (f1 & 3) * 8;
  ushort* As0 = (ushort*)As + wave * 2 * 512;
  ushort* As1 = As0 + 512;
  ushort* Bs0 = (ushort*)Bs + wave * 2 * 512;
  ushort* Bs1 = Bs0 + 512;

  for (int k0 = 0; k0 < K; k0 += 32) {
    gload_lds16(A + (long)(bm + r0) * lda + k0 + c0, As0);
    gload_lds16(A + (long)(bm + r1) * lda + k0 + c1, As1);
    gload_lds16(Bt + (long)(bn + r0) * K + k0 + c0, Bs0);
    gload_lds16(Bt + (long)(bn + r1) * K + k0 + c1, Bs1);
    __syncthreads();

    bf16x8 af[4], bfr[4];
#pragma unroll
    for (int f = 0; f < 4; ++f) {
      af[f]  = *(const bf16x8*)&As[wm + f * 16 + fr][fk];
      bfr[f] = *(const bf16x8*)&Bs[wn + f * 16 + fr][fk];
    }
#pragma unroll
    for (int mf = 0; mf < 4; ++mf)
#pragma unroll
      for (int nf = 0; nf < 4; ++nf)
        acc[mf][nf] = __builtin_amdgcn_mfma_f32_16x16x32_bf16(
            af[mf], bfr[nf], acc[mf][nf], 0, 0, 0);
    __syncthreads();
  }

  float bv[4];
#pragma unroll
  for (int nf = 0; nf < 4; ++nf)
    bv[nf] = HASBIAS ? bias[bn + wn + nf * 16 + fr] : 0.f;

  const int crow0 = (lane >> 4) * 4;
#pragma unroll
  for (int mf = 0; mf < 4; ++mf)
#pragma unroll
    for (int r = 0; r < 4; ++r) {
      const long roff = (long)(bm + wm + mf * 16 + crow0 + r) * ldc + bn + wn;
#pragma unroll
      for (int nf = 0; nf < 4; ++nf) {
        float v = acc[mf][nf][r] + bv[nf];
        if (OUTBF) {
          unsigned u = __float_as_uint(v);
          u += 0x7fffu + ((u >> 16) & 1u);
          Cb[roff + nf * 16 + fr] = (ushort)(u >> 16);
        } else {
          if (ACCUM) v += Cf[roff + nf * 16 + fr];
          if (RELU) v = fmaxf(v, 0.f);
          Cf[roff + nf * 16 + fr] = v;
        }
      }
    }
}

// ---------------------------------------------------------------------------
// helpers
// ---------------------------------------------------------------------------
__device__ __forceinline__ unsigned short f2bf(float f) {
  unsigned u = __float_as_uint(f);
  u += 0x7fffu + ((u >> 16) & 1u);
  return (unsigned short)(u >> 16);
}
__device__ __forceinline__ float bf2f(ushort v) {
  return __uint_as_float(((unsigned)v) << 16);
}
__device__ __forceinline__ float fast_sig(float x) {
  return __builtin_amdgcn_rcpf(1.f + __expf(-x));
}
__device__ __forceinline__ float fast_tanh(float x) {
  return 2.f * fast_sig(2.f * x) - 1.f;
}

__device__ __forceinline__ int sdot4_(uint a, uint b, int c) {
#if __has_builtin(__builtin_amdgcn_sdot4)
  return __builtin_amdgcn_sdot4((int)a, (int)b, c, false);
#else
  int r = c;
  r += ((int)(a << 24) >> 24) * ((int)(b << 24) >> 24);
  r += ((int)(a << 16) >> 24) * ((int)(b << 16) >> 24);
  r += ((int)(a << 8)  >> 24) * ((int)(b << 8)  >> 24);
  r += ((int)a >> 24)         * ((int)b >> 24);
  return r;
#endif
}

// Fused f32->bf16 conversions: U (8192 blocks) + Wih0 (2048) + Wih1 (1024)
__global__ __launch_bounds__(256) void cvt_all_k(
    const float* __restrict__ U, ushort* __restrict__ ubf,
    const float* __restrict__ W0, ushort* __restrict__ w0,
    const float* __restrict__ W1, ushort* __restrict__ w1)
{
  const int bid = blockIdx.x;
  const float* src; ushort* dst; long base;
  if (bid < 8192)       { src = U;  dst = ubf; base = (long)bid * 1024; }
  else if (bid < 10240) { src = W0; dst = w0;  base = (long)(bid - 8192) * 1024; }
  else                  { src = W1; dst = w1;  base = (long)(bid - 10240) * 1024; }
  const long i = base + threadIdx.x * 4;
  float4 v = *(const float4*)(src + i);
  ushort4 o;
  o.x = f2bf(v.x); o.y = f2bf(v.y); o.z = f2bf(v.z); o.w = f2bf(v.w);
  *(ushort4*)(dst + i) = o;
}

// Fused transpose+bf16 for the weight matrices. Each job: dst[c*dstStride +
// dstOff + r] = src[r*C + c]. gc_W1/gc_W2 stack into one 256x512 matrix.
__global__ __launch_bounds__(256) void tp_all_k(
    const float* __restrict__ s0, ushort* __restrict__ d0,   // W_root 512x256
    const float* __restrict__ s1, const float* __restrict__ s2,
    ushort* __restrict__ d12,                                // gc stacked 256x512
    const float* __restrict__ s3, ushort* __restrict__ d3,   // Wm 768x768
    const float* __restrict__ s4, ushort* __restrict__ d4,   // Wl 768x256
    const float* __restrict__ s5, ushort* __restrict__ d5)   // W_scalar 512x128
{
  __shared__ float tile[32][33];
  const int bid = blockIdx.x;
  const float* src; ushort* dst; int C, gx, local, dstStride, dstOff;
  if (bid < 128)       { src = s0; dst = d0;  C = 256; gx = 8;  local = bid;        dstStride = 512; dstOff = 0; }
  else if (bid < 192)  { src = s1; dst = d12; C = 256; gx = 8;  local = bid - 128;  dstStride = 512; dstOff = 0; }
  else if (bid < 256)  { src = s2; dst = d12; C = 256; gx = 8;  local = bid - 192;  dstStride = 512; dstOff = 256; }
  else if (bid < 832)  { src = s3; dst = d3;  C = 768; gx = 24; local = bid - 256;  dstStride = 768; dstOff = 0; }
  else if (bid < 1024) { src = s4; dst = d4;  C = 256; gx = 8;  local = bid - 832;  dstStride = 768; dstOff = 0; }
  else                 { src = s5; dst = d5;  C = 128; gx = 4;  local = bid - 1024; dstStride = 512; dstOff = 0; }
  const int c0 = (local % gx) * 32, r0 = (local / gx) * 32;
  const int tx = threadIdx.x & 31, ty = threadIdx.x >> 5;
#pragma unroll
  for (int j = 0; j < 4; ++j)
    tile[ty + j * 8][tx] = src[(long)(r0 + ty + j * 8) * C + c0 + tx];
  __syncthreads();
#pragma unroll
  for (int j = 0; j < 4; ++j)
    dst[(long)(c0 + ty + j * 8) * dstStride + dstOff + r0 + tx] = f2bf(tile[tx][ty + j * 8]);
}

// Fused Whh pack (both layers): (2,1024,256) f32 -> int8 dwords + scales
__global__ __launch_bounds__(256) void pack_whh_all_k(
    const float* __restrict__ Whh0, const float* __restrict__ Whh1,
    uint* __restrict__ Wq, float* __restrict__ fscale)
{
  const int wid = (blockIdx.x * 256 + threadIdx.x) >> 6;  // 0..4095
  const int lane = threadIdx.x & 63;
  const int l = wid >> 11;
  const int wid2 = wid & 2047;
  const int d = wid2 >> 10, gi = wid2 & 1023;
  const float* Whh = l ? Whh1 : Whh0;
  const float* row = Whh + ((long)d * 1024 + gi) * 256 + lane * 4;
  float v0 = row[0], v1 = row[1], v2 = row[2], v3 = row[3];
  float am = fmaxf(fmaxf(fabsf(v0), fabsf(v1)), fmaxf(fabsf(v2), fabsf(v3)));
#pragma unroll
  for (int off = 32; off > 0; off >>= 1) am = fmaxf(am, __shfl_xor(am, off, 64));
  am = fmaxf(am, 1e-12f);
  const float inv = 127.f / am;
  int q0 = __float2int_rn(v0 * inv), q1 = __float2int_rn(v1 * inv);
  int q2 = __float2int_rn(v2 * inv), q3 = __float2int_rn(v3 * inv);
  uint w = (uint)(q0 & 255) | ((uint)(q1 & 255) << 8) |
           ((uint)(q2 & 255) << 16) | ((uint)(q3 & 255) << 24);
  Wq[(long)l * 131072 + ((long)d * 64 + lane) * 1024 + gi] = w;
  if (lane == 0) fscale[l * 2048 + d * 1024 + gi] = am / 127.f;
}

// ---------------------------------------------------------------------------
// LSTM v4L: lstm4 with HYBRID weight residency — 32 k4-slices (128 KB)
// preloaded into LDS once, 32 slices streamed from L2 per step. Halves the
// per-XCD L2 stream (was at 91% of the 4.3 TB/s ceiling); LDS path (128 KB
// per step at ~128 B/cyc) overlaps the L2 path. Same math/order as lstm4.
// ---------------------------------------------------------------------------
#define WL 32   // k4 slices resident in LDS

__global__ __launch_bounds__(1024) void lstm4_k(
    const float* __restrict__ Xg,
    const uint* __restrict__ Wq,
    const float* __restrict__ fscale,
    ushort* __restrict__ out,
    int bmajor, long ldo)
{
  const int bx = blockIdx.x;
  const int d = bx >> 6, b = bx & 63;
  const int tid = threadIdx.x;

  __shared__ uint wlds[WL * 1024];   // 128 KB
  __shared__ uint hq[2][64];
  __shared__ float preactF[1024];

  const uint* wrow = Wq + (long)d * 65536 + tid;
  // preload LDS-resident half (coalesced, conflict-free [k4][tid] layout)
#pragma unroll
  for (int k4 = 0; k4 < WL; ++k4) wlds[k4 * 1024 + tid] = wrow[k4 * 1024];
  const uint* wstr = wrow + WL * 1024;   // streamed half

  if (tid < 128) ((uint*)hq)[tid] = 0u;

  const float fsc = fscale[d * 1024 + tid] * (1.0f / 127.0f);
  const float* Xd = Xg + (long)d * 8192 * 1024;

  float c = 0.f;
  float x0 = 0.f, x1 = 0.f, x2 = 0.f, x3 = 0.f;
  if (tid < 256) {
    const float* xr = Xd + ((long)((d ? 127 : 0) * 64 + b)) * 1024;
    x0 = xr[tid]; x1 = xr[tid + 256]; x2 = xr[tid + 512]; x3 = xr[tid + 768];
  }
  __syncthreads();

  int cur = 0;
  for (int step = 0; step < 128; ++step) {
    const int t = d ? 127 - step : step;

    float n0 = 0.f, n1 = 0.f, n2 = 0.f, n3 = 0.f;
    if (tid < 256 && step + 1 < 128) {
      const float* xr = Xd + ((long)((d ? 126 - step : step + 1) * 64 + b)) * 1024;
      n0 = xr[tid]; n1 = xr[tid + 256]; n2 = xr[tid + 512]; n3 = xr[tid + 768];
    }

    int acc = 0;
    const uint4* hrow = (const uint4*)hq[cur];
    // LDS-resident half (k4 = 0..31)
#pragma unroll
    for (int k16 = 0; k16 < WL / 4; ++k16) {
      uint4 h4 = hrow[k16];
      acc = sdot4_(wlds[(k16 * 4 + 0) * 1024 + tid], h4.x, acc);
      acc = sdot4_(wlds[(k16 * 4 + 1) * 1024 + tid], h4.y, acc);
      acc = sdot4_(wlds[(k16 * 4 + 2) * 1024 + tid], h4.z, acc);
      acc = sdot4_(wlds[(k16 * 4 + 3) * 1024 + tid], h4.w, acc);
    }
    // L2-streamed half (k4 = 32..63)
#pragma unroll
    for (int k16 = WL / 4; k16 < 16; ++k16) {
      uint4 h4 = hrow[k16];
      acc = sdot4_(wstr[((k16 - WL / 4) * 4 + 0) * 1024], h4.x, acc);
      acc = sdot4_(wstr[((k16 - WL / 4) * 4 + 1) * 1024], h4.y, acc);
      acc = sdot4_(wstr[((k16 - WL / 4) * 4 + 2) * 1024], h4.z, acc);
      acc = sdot4_(wstr[((k16 - WL / 4) * 4 + 3) * 1024], h4.w, acc);
    }
    preactF[tid] = (float)acc * fsc;
    __syncthreads();

    if (tid < 256) {
      float p0 = x0 + preactF[tid];
      float p1 = x1 + preactF[tid + 256];
      float p2 = x2 + preactF[tid + 512];
      float p3 = x3 + preactF[tid + 768];
      const float ig = fast_sig(p0), fg = fast_sig(p1);
      const float gg = fast_tanh(p2), og = fast_sig(p3);
      c = fg * c + ig * gg;
      const float h = og * fast_tanh(c);
      const long row = bmajor ? ((long)b * 128 + t) : ((long)t * 64 + b);
      out[row * ldo + (d << 8) + tid] = f2bf(h);
      ((char*)hq[cur ^ 1])[tid] = (char)__float2int_rn(h * 127.f);
      x0 = n0; x1 = n1; x2 = n2; x3 = n3;
    }
    __syncthreads();
    cur ^= 1;
  }
}

// W_rel basis combination -> bf16 transposed (N=r*256+o rows, K=f cols)
__global__ __launch_bounds__(256) void wrel_k(const float* __restrict__ basis,
                                              const float* __restrict__ comp,
                                              ushort* __restrict__ wrel2t) {
  const int f = blockIdx.x;     // 0..511
  const int o = threadIdx.x;    // 0..255
  __shared__ float cs[240];
  if (o < 240) cs[o] = comp[o];
  __syncthreads();
  float acc[8];
#pragma unroll
  for (int r = 0; r < 8; ++r) acc[r] = 0.f;
  for (int bb = 0; bb < 30; ++bb) {
    const float v = basis[((long)bb * 512 + f) * 256 + o];
#pragma unroll
    for (int r = 0; r < 8; ++r) acc[r] = fmaf(cs[r * 30 + bb], v, acc[r]);
  }
#pragma unroll
  for (int r = 0; r < 8; ++r)
    wrel2t[((long)(r * 256 + o)) * 512 + f] = f2bf(acc[r]);
}

// ---------------------------------------------------------------------------
// RGCN gather FUSED with edge-attention softmax (proven). Writes the h half
// of the [8192][512] {h|agg} buffer.
// ---------------------------------------------------------------------------
__global__ __launch_bounds__(256) void rgcn_fused_k(
    const float* __restrict__ scale, const ushort* __restrict__ xrel,
    const float* __restrict__ hroot, const int* __restrict__ spk,
    ushort* __restrict__ hagg)
{
  const int n = blockIdx.x;
  const int b = n >> 7, t = n & 127;
  const int o = threadIdx.x;
  const int lo = max(t - 10, 0), hi = min(t + 10, 127);
  const int cnt = hi - lo + 1;

  __shared__ float sc[128], red[128];
  __shared__ int spks[21];
  __shared__ int spkt_s;

  if (o < 128) {
    const float v = scale[((long)(b * 128 + o)) * 128 + t];
    sc[o] = v; red[o] = v;
  }
  if (o == 0) spkt_s = spk[t * 64 + b];
  if (o >= 128 && o - 128 < cnt) spks[o - 128] = spk[(lo + o - 128) * 64 + b];
  __syncthreads();
  for (int off = 64; off > 0; off >>= 1) {
    if (o < off) red[o] = fmaxf(red[o], red[o + off]);
    __syncthreads();
  }
  const float m = red[0];
  __syncthreads();
  if (o < 128) {
    const float e = expf(sc[o] - m);
    sc[o] = e;
    const int dd = o - t;
    const bool inwin = (dd <= 10) && (dd >= -10);
    red[o] = e * (inwin ? 1.0f : 1e-10f);
  }
  __syncthreads();
  for (int off = 64; off > 0; off >>= 1) {
    if (o < off) red[o] += red[o + off];
    __syncthreads();
  }
  const float inv_msum = 1.0f / red[0];
  __syncthreads();

  const int spkt = spkt_s;
  float acc = hroot[(long)n * 256 + o];
  for (int q = 0; q < cnt; ++q) {
    const int s = lo + q;
    const float wv = sc[s] * inv_msum;
    const int et = spkt * 4 + spks[q] * 2 + ((t < s) ? 0 : 1);
    acc = fmaf(bf2f(xrel[(((long)(b * 128 + s)) * 8 + et) * 256 + o]), wv, acc);
  }
  hagg[(long)n * 512 + o] = f2bf(acc);
}

// GraphConv neighbor aggregation: reads h half, writes agg half (cols 256+)
__global__ __launch_bounds__(256) void agg_k(ushort* __restrict__ hagg) {
  const int n = blockIdx.x;
  const int b = n >> 7, t = n & 127;
  const int o = threadIdx.x;
  const int lo = max(t - 10, 0), hi = min(t + 10, 127);
  float acc = 0.f;
  for (int s = lo; s <= hi; ++s) acc += bf2f(hagg[((long)(b * 128 + s)) * 512 + o]);
  hagg[(long)n * 512 + 256 + o] = f2bf(acc);
}

// Batched ushort transpose: dst[b](C x R) = src[b](R x C)^T, R=128, C=768.
__global__ __launch_bounds__(256) void emt_k(const ushort* __restrict__ src,
                                             ushort* __restrict__ dst) {
  __shared__ ushort tile[32][33];
  const int c0 = blockIdx.x * 32;
  const int r0 = blockIdx.y * 32;
  const int b = blockIdx.z;
  const ushort* s = src + (long)b * 98304;
  ushort* d = dst + (long)b * 98304;
  const int tx = threadIdx.x & 31, ty = threadIdx.x >> 5;
#pragma unroll
  for (int j = 0; j < 4; ++j)
    tile[ty + j * 8][tx] = s[(long)(r0 + ty + j * 8) * 768 + c0 + tx];
  __syncthreads();
#pragma unroll
  for (int j = 0; j < 4; ++j)
    d[(long)(c0 + ty + j * 8) * 128 + r0 + tx] = tile[tx][ty + j * 8];
}

// Matching attention probs: logits f32 in, bf16 a out
__global__ __launch_bounds__(128) void match_softmax_k(const float* __restrict__ logits,
                                                       const float* __restrict__ umask,
                                                       ushort* __restrict__ abf) {
  const int bx = blockIdx.x;           // b*128 + t
  const int b = bx >> 7;
  const int s = threadIdx.x;
  __shared__ float red[128];
  const float* row = logits + (long)bx * 128;
  const float um = umask[b * 128 + s];
  const float v = tanhf(row[s] * um * um);
  red[s] = v; __syncthreads();
  for (int off = 64; off > 0; off >>= 1) { if (s < off) red[s] = fmaxf(red[s], red[s + off]); __syncthreads(); }
  const float m = red[0]; __syncthreads();
  const float e = expf(v - m);
  red[s] = e; __syncthreads();
  for (int off = 64; off > 0; off >>= 1) { if (s < off) red[s] += red[s + off]; __syncthreads(); }
  const float es = red[0]; __syncthreads();
  const float p = (e / es) * um;
  red[s] = p; __syncthreads();
  for (int off = 64; off > 0; off >>= 1) { if (s < off) red[s] += red[s + off]; __syncthreads(); }
  const float ps = red[0];
  abf[(long)bx * 128 + s] = f2bf(p / ps);
}

__global__ __launch_bounds__(256) void final_k(const float* __restrict__ hidden,
                                               const float* __restrict__ Ws,
                                               const float* __restrict__ bs,
                                               float* __restrict__ out) {
  __shared__ float wsl[256 * 6];
  const int tid = threadIdx.x;
#pragma unroll
  for (int j = 0; j < 6; ++j) wsl[tid * 6 + j] = Ws[tid * 6 + j];
  __syncthreads();
  const int wave = tid >> 6, lane = tid & 63;
  const int n = blockIdx.x * 4 + wave;
  const float4 hv = *(const float4*)&hidden[(long)n * 256 + lane * 4];
  const float hvv[4] = {hv.x, hv.y, hv.z, hv.w};
  float a[6];
#pragma unroll
  for (int c = 0; c < 6; ++c) a[c] = 0.f;
#pragma unroll
  for (int j = 0; j < 4; ++j)
#pragma unroll
    for (int c = 0; c < 6; ++c)
      a[c] = fmaf(hvv[j], wsl[(lane * 4 + j) * 6 + c], a[c]);
#pragma unroll
  for (int off = 32; off > 0; off >>= 1)
#pragma unroll
    for (int c = 0; c < 6; ++c)
      a[c] += __shfl_xor(a[c], off, 64);
  if (lane == 0) {
    float v[6], m = -1e30f;
#pragma unroll
    for (int c = 0; c < 6; ++c) { v[c] = a[c] + bs[c]; m = fmaxf(m, v[c]); }
    float sum = 0.f;
#pragma unroll
    for (int c = 0; c < 6; ++c) sum += expf(v[c] - m);
    const float lse = m + logf(sum);
#pragma unroll
    for (int c = 0; c < 6; ++c) out[(long)n * 6 + c] = v[c] - lse;
  }
}

// ---------------------------------------------------------------------------
// Orchestration
// ---------------------------------------------------------------------------
extern "C" void kernel_launch(void* const* d_in, const int* in_sizes, int n_in,
                              void* d_out, int out_size, void* d_ws, size_t ws_size,
                              hipStream_t stream) {
  const float* U        = (const float*)d_in[0];
  const float* umask    = (const float*)d_in[1];
  const float* Wih0     = (const float*)d_in[2];
  const float* Whh0     = (const float*)d_in[3];
  const float* b0       = (const float*)d_in[4];
  const float* Wih1     = (const float*)d_in[5];
  const float* Whh1     = (const float*)d_in[6];
  const float* b1       = (const float*)d_in[7];
  const float* W_scalar = (const float*)d_in[8];
  const float* basis    = (const float*)d_in[9];
  const float* comp     = (const float*)d_in[10];
  const float* W_root   = (const float*)d_in[11];
  const float* b_rgcn   = (const float*)d_in[12];
  const float* gc_W1    = (const float*)d_in[13];
  const float* gc_W2    = (const float*)d_in[14];
  const float* gc_b     = (const float*)d_in[15];
  const float* Wm       = (const float*)d_in[16];
  const float* bm       = (const float*)d_in[17];
  const float* Wl       = (const float*)d_in[18];
  const float* bl       = (const float*)d_in[19];
  const float* Wsw      = (const float*)d_in[20];
  const float* bsw      = (const float*)d_in[21];
  const int*   speakers = (const int*)d_in[22];

  float* ws = (float*)d_ws;
  // Regions (float offsets), lifetimes audited:
  float* gates   = ws + 0L;          // 16.78M f: gates0/1 -> xrelbf -> xtrbf
  float* feats   = ws + 16777216L;   //  4.19M f: wih0bf/wih1bf -> attbf
  float* xbuf    = ws + 20971520L;   //  4.19M f: ubf -> hagg -> emT
  float* feats0  = ws + 25165824L;   //  4.19M f: f0bf -> xemb [8192][768]
  float* scaleb  = ws + 29360128L;   //  1.05M f: scale -> logits -> hidden(lo)
  float* scoresb = ws + 30408704L;   //  1.05M f: wscT -> abf -> hidden(hi)
  float* wrelr   = ws + 31457280L;   //  1.05M f: wrel2t bf16
  float* hroot   = ws + 32505856L;   //  2.10M f: hroot f32
  uint*  wq      = (uint*)(ws + 34603008L);   // 262,144 dwords
  float* fsc     = ws + 34865152L;            // 4,096
  float* wTr     = ws + 34869248L;            // 524,288 f (transposed weights)

  ushort* ubf    = (ushort*)xbuf;
  ushort* wih0bf = (ushort*)feats;
  ushort* wih1bf = (ushort*)(feats + 1048576L);
  ushort* f0bf   = (ushort*)feats0;              // dead after gates L1 gemm
  ushort* xemb   = (ushort*)feats0;              // [8192][768]: x | gc-out
  ushort* wrel2t = (ushort*)wrelr;
  ushort* wroott = (ushort*)wTr;                 // 131,072 us (256 x 512)
  ushort* gcW12t = wroott + 131072L;             // 131,072 us (256 x 512 stacked)
  ushort* Wmt    = gcW12t + 131072L;             // 589,824 us
  ushort* Wlt    = Wmt + 589824L;                // 196,608 us
  ushort* wscT   = (ushort*)scoresb;             // 65,536 us (dead after scale gemm)

  ushort* hagg    = (ushort*)xbuf;               // [8192][512]: h | agg (ubf dead)
  ushort* emT     = (ushort*)xbuf;               // after gc gemm (hagg dead)
  ushort* xrelbf  = (ushort*)gates;
  ushort* xtrbf   = (ushort*)gates;
  ushort* abf     = (ushort*)scoresb;
  ushort* attbf   = (ushort*)feats;

  float*  logitsb = scaleb;
  float*  hiddenb = scaleb;

  // --- weight prep (4 dispatches) ---
  pack_whh_all_k<<<1024, 256, 0, stream>>>(Whh0, Whh1, wq, fsc);
  cvt_all_k<<<11264, 256, 0, stream>>>(U, ubf, Wih0, wih0bf, Wih1, wih1bf);
  tp_all_k<<<1088, 256, 0, stream>>>(W_root, wroott, gc_W1, gc_W2, gcW12t,
                                     Wm, Wmt, Wl, Wlt, W_scalar, wscT);
  wrel_k<<<512, 256, 0, stream>>>(basis, comp, wrel2t);

  // --- layer 0 ---
  gemm_bf16_nt<true, false, false, false><<<dim3(8, 64, 2), 256, 0, stream>>>(
      ubf, wih0bf, b0, gates, 8192, 1024, 1024, 1024L, 1024L,
      0L, 1048576L, 8388608L, 1024L);
  lstm4_k<<<128, 1024, 0, stream>>>(gates, wq, fsc, f0bf, 0, 512L);

  // --- layer 1 (writes x directly into xemb cols [0:512), b-major) ---
  gemm_bf16_nt<true, false, false, false><<<dim3(8, 64, 2), 256, 0, stream>>>(
      f0bf, wih1bf, b1, gates, 8192, 1024, 512, 512L, 1024L,
      0L, 524288L, 8388608L, 1024L);
  lstm4_k<<<128, 1024, 0, stream>>>(gates, wq + 131072, fsc + 2048, xemb, 1, 768L);

  // --- edge scale + RGCN ---
  gemm_bf16_nt<false, false, false, false><<<dim3(1, 64, 1), 256, 0, stream>>>(
      xemb, wscT, nullptr, scaleb, 8192, 128, 512, 768L, 128L, 0L, 0L, 0L, 0L);
  gemm_bf16_nt<true, false, false, false><<<dim3(2, 64, 1), 256, 0, stream>>>(
      xemb, wroott, b_rgcn, hroot, 8192, 256, 512, 768L, 256L, 0L, 0L, 0L, 0L);
  gemm_bf16_nt<false, false, false, true><<<dim3(16, 64, 1), 256, 0, stream>>>(
      xemb, wrel2t, nullptr, xrelbf, 8192, 2048, 512, 768L, 2048L, 0L, 0L, 0L, 0L);
  rgcn_fused_k<<<8192, 256, 0, stream>>>(scaleb, xrelbf, hroot, speakers, hagg);

  // --- GraphConv (merged: [h|agg] @ [W1;W2] + b -> xemb cols [512:768)) ---
  agg_k<<<8192, 256, 0, stream>>>(hagg);
  gemm_bf16_nt<true, false, false, true><<<dim3(2, 64, 1), 256, 0, stream>>>(
      hagg, gcW12t, gc_b, xemb + 512, 8192, 256, 512, 512L, 768L, 0L, 0L, 0L, 0L);

  // --- matching attention ---
  gemm_bf16_nt<true, false, false, true><<<dim3(6, 64, 1), 256, 0, stream>>>(
      xemb, Wmt, bm, xtrbf, 8192, 768, 768, 768L, 768L, 0L, 0L, 0L, 0L);
  emt_k<<<dim3(24, 4, 64), 256, 0, stream>>>(xemb, emT);
  gemm_bf16_nt<false, false, false, false><<<dim3(1, 1, 64), 256, 0, stream>>>(
      xtrbf, xemb, nullptr, logitsb, 128, 128, 768, 768L, 128L,
      98304L, 98304L, 16384L, 0L);
  match_softmax_k<<<8192, 128, 0, stream>>>(logitsb, umask, abf);
  gemm_bf16_nt<false, false, false, true><<<dim3(6, 1, 64), 256, 0, stream>>>(
      abf, emT, nullptr, attbf, 128, 768, 128, 128L, 768L,
      16384L, 98304L, 98304L, 0L);

  // --- classifier ---
  gemm_bf16_nt<true, false, true, false><<<dim3(2, 64, 1), 256, 0, stream>>>(
      attbf, Wlt, bl, hiddenb, 8192, 256, 768, 768L, 256L, 0L, 0L, 0L, 0L);
  final_k<<<2048, 256, 0, stream>>>(hiddenb, Wsw, bsw, (float*)d_out);
}

// Round 15
// 610.946 us; speedup vs baseline: 1.2699x; 1.2699x over previous
//
#include <hip/hip_runtime.h>
#include <cstdint>

// Model dims (fixed): L=128, B=64, DM=1024, H=256, F=512, HID=256, MEM=768,
// N=B*L=8192, NC=6, R=8, NB=30, WIN=10

typedef __attribute__((ext_vector_type(8))) short bf16x8;
typedef __attribute__((ext_vector_type(4))) float f32x4;

__device__ __forceinline__ void gload_lds16(const void* g, void* l) {
  __builtin_amdgcn_global_load_lds(
      (const __attribute__((address_space(1))) void*)g,
      (__attribute__((address_space(3))) void*)l, 16, 0, 0);
}

// ---------------------------------------------------------------------------
// bf16 NT MFMA GEMM: C(MxN) = A(MxK)bf16 @ Bt(NxK)bf16^T (+bias)(+accum)
// A row stride lda, C row stride ldc (B row stride == K). Batched via
// blockIdx.z. 128x128x32 tile, 4 waves, 16x16x32 MFMA, global_load_lds.
// ---------------------------------------------------------------------------
template<bool HASBIAS, bool ACCUM, bool RELU, bool OUTBF>
__global__ __launch_bounds__(256) void gemm_bf16_nt(
    const ushort* __restrict__ A, const ushort* __restrict__ Bt,
    const float* __restrict__ bias, void* __restrict__ Cv,
    int M, int N, int K, long lda, long ldc,
    long sA, long sB, long sC, long sBias)
{
  const int bz = blockIdx.z;
  A += (long)bz * sA;
  Bt += (long)bz * sB;
  if (HASBIAS) bias += (long)bz * sBias;
  float*  Cf = OUTBF ? nullptr : ((float*)Cv + (long)bz * sC);
  ushort* Cb = OUTBF ? ((ushort*)Cv + (long)bz * sC) : nullptr;

  const int bn = blockIdx.x * 128, bm = blockIdx.y * 128;

  __shared__ ushort As[128][32];
  __shared__ ushort Bs[128][32];

  const int tid = threadIdx.x;
  const int wave = tid >> 6, lane = tid & 63;
  const int wm = (wave >> 1) * 64, wn = (wave & 1) * 64;
  const int fr = lane & 15;
  const int fk = (lane >> 4) * 8;

  f32x4 acc[4][4];
#pragma unroll
  for (int i = 0; i < 4; ++i)
#pragma unroll
    for (int j = 0; j < 4; ++j) acc[i][j] = (f32x4){0.f, 0.f, 0.f, 0.f};

  const int f0 = wave * 2 * 64 + lane;
  const int f1 = f0 + 64;
  const int r0 = f0 >> 2, c0 = (f0 & 3) * 8;
  const int r1 = f1 >> 2, c1 = (f1 & 3) * 8;
  ushort* As0 = (ushort*)As + wave * 2 * 512;
  ushort* As1 = As0 + 512;
  ushort* Bs0 = (ushort*)Bs + wave * 2 * 512;
  ushort* Bs1 = Bs0 + 512;

  for (int k0 = 0; k0 < K; k0 += 32) {
    gload_lds16(A + (long)(bm + r0) * lda + k0 + c0, As0);
    gload_lds16(A + (long)(bm + r1) * lda + k0 + c1, As1);
    gload_lds16(Bt + (long)(bn + r0) * K + k0 + c0, Bs0);
    gload_lds16(Bt + (long)(bn + r1) * K + k0 + c1, Bs1);
    __syncthreads();

    bf16x8 af[4], bfr[4];
#pragma unroll
    for (int f = 0; f < 4; ++f) {
      af[f]  = *(const bf16x8*)&As[wm + f * 16 + fr][fk];
      bfr[f] = *(const bf16x8*)&Bs[wn + f * 16 + fr][fk];
    }
#pragma unroll
    for (int mf = 0; mf < 4; ++mf)
#pragma unroll
      for (int nf = 0; nf < 4; ++nf)
        acc[mf][nf] = __builtin_amdgcn_mfma_f32_16x16x32_bf16(
            af[mf], bfr[nf], acc[mf][nf], 0, 0, 0);
    __syncthreads();
  }

  float bv[4];
#pragma unroll
  for (int nf = 0; nf < 4; ++nf)
    bv[nf] = HASBIAS ? bias[bn + wn + nf * 16 + fr] : 0.f;

  const int crow0 = (lane >> 4) * 4;
#pragma unroll
  for (int mf = 0; mf < 4; ++mf)
#pragma unroll
    for (int r = 0; r < 4; ++r) {
      const long roff = (long)(bm + wm + mf * 16 + crow0 + r) * ldc + bn + wn;
#pragma unroll
      for (int nf = 0; nf < 4; ++nf) {
        float v = acc[mf][nf][r] + bv[nf];
        if (OUTBF) {
          unsigned u = __float_as_uint(v);
          u += 0x7fffu + ((u >> 16) & 1u);
          Cb[roff + nf * 16 + fr] = (ushort)(u >> 16);
        } else {
          if (ACCUM) v += Cf[roff + nf * 16 + fr];
          if (RELU) v = fmaxf(v, 0.f);
          Cf[roff + nf * 16 + fr] = v;
        }
      }
    }
}

// ---------------------------------------------------------------------------
// helpers
// ---------------------------------------------------------------------------
__device__ __forceinline__ unsigned short f2bf(float f) {
  unsigned u = __float_as_uint(f);
  u += 0x7fffu + ((u >> 16) & 1u);
  return (unsigned short)(u >> 16);
}
__device__ __forceinline__ float bf2f(ushort v) {
  return __uint_as_float(((unsigned)v) << 16);
}
__device__ __forceinline__ float fast_sig(float x) {
  return __builtin_amdgcn_rcpf(1.f + __expf(-x));
}
__device__ __forceinline__ float fast_tanh(float x) {
  return 2.f * fast_sig(2.f * x) - 1.f;
}

__device__ __forceinline__ int sdot4_(uint a, uint b, int c) {
#if __has_builtin(__builtin_amdgcn_sdot4)
  return __builtin_amdgcn_sdot4((int)a, (int)b, c, false);
#else
  int r = c;
  r += ((int)(a << 24) >> 24) * ((int)(b << 24) >> 24);
  r += ((int)(a << 16) >> 24) * ((int)(b << 16) >> 24);
  r += ((int)(a << 8)  >> 24) * ((int)(b << 8)  >> 24);
  r += ((int)a >> 24)         * ((int)b >> 24);
  return r;
#endif
}

// Fused f32->bf16 conversions: U (8192 blocks) + Wih0 (2048) + Wih1 (1024)
__global__ __launch_bounds__(256) void cvt_all_k(
    const float* __restrict__ U, ushort* __restrict__ ubf,
    const float* __restrict__ W0, ushort* __restrict__ w0,
    const float* __restrict__ W1, ushort* __restrict__ w1)
{
  const int bid = blockIdx.x;
  const float* src; ushort* dst; long base;
  if (bid < 8192)       { src = U;  dst = ubf; base = (long)bid * 1024; }
  else if (bid < 10240) { src = W0; dst = w0;  base = (long)(bid - 8192) * 1024; }
  else                  { src = W1; dst = w1;  base = (long)(bid - 10240) * 1024; }
  const long i = base + threadIdx.x * 4;
  float4 v = *(const float4*)(src + i);
  ushort4 o;
  o.x = f2bf(v.x); o.y = f2bf(v.y); o.z = f2bf(v.z); o.w = f2bf(v.w);
  *(ushort4*)(dst + i) = o;
}

// Fused transpose+bf16 for the weight matrices. Each job: dst[c*dstStride +
// dstOff + r] = src[r*C + c]. gc_W1/gc_W2 stack into one 256x512 matrix.
__global__ __launch_bounds__(256) void tp_all_k(
    const float* __restrict__ s0, ushort* __restrict__ d0,   // W_root 512x256
    const float* __restrict__ s1, const float* __restrict__ s2,
    ushort* __restrict__ d12,                                // gc stacked 256x512
    const float* __restrict__ s3, ushort* __restrict__ d3,   // Wm 768x768
    const float* __restrict__ s4, ushort* __restrict__ d4,   // Wl 768x256
    const float* __restrict__ s5, ushort* __restrict__ d5)   // W_scalar 512x128
{
  __shared__ float tile[32][33];
  const int bid = blockIdx.x;
  const float* src; ushort* dst; int C, gx, local, dstStride, dstOff;
  if (bid < 128)       { src = s0; dst = d0;  C = 256; gx = 8;  local = bid;        dstStride = 512; dstOff = 0; }
  else if (bid < 192)  { src = s1; dst = d12; C = 256; gx = 8;  local = bid - 128;  dstStride = 512; dstOff = 0; }
  else if (bid < 256)  { src = s2; dst = d12; C = 256; gx = 8;  local = bid - 192;  dstStride = 512; dstOff = 256; }
  else if (bid < 832)  { src = s3; dst = d3;  C = 768; gx = 24; local = bid - 256;  dstStride = 768; dstOff = 0; }
  else if (bid < 1024) { src = s4; dst = d4;  C = 256; gx = 8;  local = bid - 832;  dstStride = 768; dstOff = 0; }
  else                 { src = s5; dst = d5;  C = 128; gx = 4;  local = bid - 1024; dstStride = 512; dstOff = 0; }
  const int c0 = (local % gx) * 32, r0 = (local / gx) * 32;
  const int tx = threadIdx.x & 31, ty = threadIdx.x >> 5;
#pragma unroll
  for (int j = 0; j < 4; ++j)
    tile[ty + j * 8][tx] = src[(long)(r0 + ty + j * 8) * C + c0 + tx];
  __syncthreads();
#pragma unroll
  for (int j = 0; j < 4; ++j)
    dst[(long)(c0 + ty + j * 8) * dstStride + dstOff + r0 + tx] = f2bf(tile[tx][ty + j * 8]);
}

// Fused Whh pack (both layers): (2,1024,256) f32 -> int8 dwords + scales
__global__ __launch_bounds__(256) void pack_whh_all_k(
    const float* __restrict__ Whh0, const float* __restrict__ Whh1,
    uint* __restrict__ Wq, float* __restrict__ fscale)
{
  const int wid = (blockIdx.x * 256 + threadIdx.x) >> 6;  // 0..4095
  const int lane = threadIdx.x & 63;
  const int l = wid >> 11;
  const int wid2 = wid & 2047;
  const int d = wid2 >> 10, gi = wid2 & 1023;
  const float* Whh = l ? Whh1 : Whh0;
  const float* row = Whh + ((long)d * 1024 + gi) * 256 + lane * 4;
  float v0 = row[0], v1 = row[1], v2 = row[2], v3 = row[3];
  float am = fmaxf(fmaxf(fabsf(v0), fabsf(v1)), fmaxf(fabsf(v2), fabsf(v3)));
#pragma unroll
  for (int off = 32; off > 0; off >>= 1) am = fmaxf(am, __shfl_xor(am, off, 64));
  am = fmaxf(am, 1e-12f);
  const float inv = 127.f / am;
  int q0 = __float2int_rn(v0 * inv), q1 = __float2int_rn(v1 * inv);
  int q2 = __float2int_rn(v2 * inv), q3 = __float2int_rn(v3 * inv);
  uint w = (uint)(q0 & 255) | ((uint)(q1 & 255) << 8) |
           ((uint)(q2 & 255) << 16) | ((uint)(q3 & 255) << 24);
  Wq[(long)l * 131072 + ((long)d * 64 + lane) * 1024 + gi] = w;
  if (lane == 0) fscale[l * 2048 + d * 1024 + gi] = am / 127.f;
}

// ---------------------------------------------------------------------------
// LSTM v4 (proven, at per-XCD L2-BW roofline — 4 redesigns all regressed):
// int8 weights streamed from L2, int8 h via LDS broadcast, sdot4; bf16
// output with row stride ldo.
// ---------------------------------------------------------------------------
__global__ __launch_bounds__(1024) void lstm4_k(
    const float* __restrict__ Xg,
    const uint* __restrict__ Wq,
    const float* __restrict__ fscale,
    ushort* __restrict__ out,
    int bmajor, long ldo)
{
  const int bx = blockIdx.x;
  const int d = bx >> 6, b = bx & 63;
  const int tid = threadIdx.x;

  __shared__ uint hq[2][64];
  __shared__ float preactF[1024];

  uint w[64];
  const uint* wrow = Wq + (long)d * 65536 + tid;
#pragma unroll
  for (int k4 = 0; k4 < 64; ++k4) w[k4] = wrow[k4 * 1024];

  if (tid < 128) ((uint*)hq)[tid] = 0u;

  const float fsc = fscale[d * 1024 + tid] * (1.0f / 127.0f);
  const float* Xd = Xg + (long)d * 8192 * 1024;

  float c = 0.f;
  float x0 = 0.f, x1 = 0.f, x2 = 0.f, x3 = 0.f;
  if (tid < 256) {
    const float* xr = Xd + ((long)((d ? 127 : 0) * 64 + b)) * 1024;
    x0 = xr[tid]; x1 = xr[tid + 256]; x2 = xr[tid + 512]; x3 = xr[tid + 768];
  }
  __syncthreads();

  int cur = 0;
  for (int step = 0; step < 128; ++step) {
    const int t = d ? 127 - step : step;

    float n0 = 0.f, n1 = 0.f, n2 = 0.f, n3 = 0.f;
    if (tid < 256 && step + 1 < 128) {
      const float* xr = Xd + ((long)((d ? 126 - step : step + 1) * 64 + b)) * 1024;
      n0 = xr[tid]; n1 = xr[tid + 256]; n2 = xr[tid + 512]; n3 = xr[tid + 768];
    }

    int acc = 0;
    const uint4* hrow = (const uint4*)hq[cur];
#pragma unroll
    for (int k16 = 0; k16 < 16; ++k16) {
      uint4 h4 = hrow[k16];
      acc = sdot4_(w[k16 * 4 + 0], h4.x, acc);
      acc = sdot4_(w[k16 * 4 + 1], h4.y, acc);
      acc = sdot4_(w[k16 * 4 + 2], h4.z, acc);
      acc = sdot4_(w[k16 * 4 + 3], h4.w, acc);
    }
    preactF[tid] = (float)acc * fsc;
    __syncthreads();

    if (tid < 256) {
      float p0 = x0 + preactF[tid];
      float p1 = x1 + preactF[tid + 256];
      float p2 = x2 + preactF[tid + 512];
      float p3 = x3 + preactF[tid + 768];
      const float ig = fast_sig(p0), fg = fast_sig(p1);
      const float gg = fast_tanh(p2), og = fast_sig(p3);
      c = fg * c + ig * gg;
      const float h = og * fast_tanh(c);
      const long row = bmajor ? ((long)b * 128 + t) : ((long)t * 64 + b);
      out[row * ldo + (d << 8) + tid] = f2bf(h);
      ((char*)hq[cur ^ 1])[tid] = (char)__float2int_rn(h * 127.f);
      x0 = n0; x1 = n1; x2 = n2; x3 = n3;
    }
    __syncthreads();
    cur ^= 1;
  }
}

// W_rel basis combination -> bf16 transposed (N=r*256+o rows, K=f cols)
__global__ __launch_bounds__(256) void wrel_k(const float* __restrict__ basis,
                                              const float* __restrict__ comp,
                                              ushort* __restrict__ wrel2t) {
  const int f = blockIdx.x;     // 0..511
  const int o = threadIdx.x;    // 0..255
  __shared__ float cs[240];
  if (o < 240) cs[o] = comp[o];
  __syncthreads();
  float acc[8];
#pragma unroll
  for (int r = 0; r < 8; ++r) acc[r] = 0.f;
  for (int bb = 0; bb < 30; ++bb) {
    const float v = basis[((long)bb * 512 + f) * 256 + o];
#pragma unroll
    for (int r = 0; r < 8; ++r) acc[r] = fmaf(cs[r * 30 + bb], v, acc[r]);
  }
#pragma unroll
  for (int r = 0; r < 8; ++r)
    wrel2t[((long)(r * 256 + o)) * 512 + f] = f2bf(acc[r]);
}

// ---------------------------------------------------------------------------
// RGCN gather FUSED with edge-attention softmax (proven r11). Writes the h
// half of the [8192][512] {h|agg} buffer.
// ---------------------------------------------------------------------------
__global__ __launch_bounds__(256) void rgcn_fused_k(
    const float* __restrict__ scale, const ushort* __restrict__ xrel,
    const float* __restrict__ hroot, const int* __restrict__ spk,
    ushort* __restrict__ hagg)
{
  const int n = blockIdx.x;
  const int b = n >> 7, t = n & 127;
  const int o = threadIdx.x;
  const int lo = max(t - 10, 0), hi = min(t + 10, 127);
  const int cnt = hi - lo + 1;

  __shared__ float sc[128], red[128];
  __shared__ int spks[21];
  __shared__ int spkt_s;

  if (o < 128) {
    const float v = scale[((long)(b * 128 + o)) * 128 + t];
    sc[o] = v; red[o] = v;
  }
  if (o == 0) spkt_s = spk[t * 64 + b];
  if (o >= 128 && o - 128 < cnt) spks[o - 128] = spk[(lo + o - 128) * 64 + b];
  __syncthreads();
  for (int off = 64; off > 0; off >>= 1) {
    if (o < off) red[o] = fmaxf(red[o], red[o + off]);
    __syncthreads();
  }
  const float m = red[0];
  __syncthreads();
  if (o < 128) {
    const float e = expf(sc[o] - m);
    sc[o] = e;
    const int dd = o - t;
    const bool inwin = (dd <= 10) && (dd >= -10);
    red[o] = e * (inwin ? 1.0f : 1e-10f);
  }
  __syncthreads();
  for (int off = 64; off > 0; off >>= 1) {
    if (o < off) red[o] += red[o + off];
    __syncthreads();
  }
  const float inv_msum = 1.0f / red[0];
  __syncthreads();

  const int spkt = spkt_s;
  float acc = hroot[(long)n * 256 + o];
  for (int q = 0; q < cnt; ++q) {
    const int s = lo + q;
    const float wv = sc[s] * inv_msum;
    const int et = spkt * 4 + spks[q] * 2 + ((t < s) ? 0 : 1);
    acc = fmaf(bf2f(xrel[(((long)(b * 128 + s)) * 8 + et) * 256 + o]), wv, acc);
  }
  hagg[(long)n * 512 + o] = f2bf(acc);
}

// GraphConv neighbor aggregation: reads h half, writes agg half (cols 256+)
__global__ __launch_bounds__(256) void agg_k(ushort* __restrict__ hagg) {
  const int n = blockIdx.x;
  const int b = n >> 7, t = n & 127;
  const int o = threadIdx.x;
  const int lo = max(t - 10, 0), hi = min(t + 10, 127);
  float acc = 0.f;
  for (int s = lo; s <= hi; ++s) acc += bf2f(hagg[((long)(b * 128 + s)) * 512 + o]);
  hagg[(long)n * 512 + 256 + o] = f2bf(acc);
}

// Batched ushort transpose: dst[b](C x R) = src[b](R x C)^T, R=128, C=768.
__global__ __launch_bounds__(256) void emt_k(const ushort* __restrict__ src,
                                             ushort* __restrict__ dst) {
  __shared__ ushort tile[32][33];
  const int c0 = blockIdx.x * 32;
  const int r0 = blockIdx.y * 32;
  const int b = blockIdx.z;
  const ushort* s = src + (long)b * 98304;
  ushort* d = dst + (long)b * 98304;
  const int tx = threadIdx.x & 31, ty = threadIdx.x >> 5;
#pragma unroll
  for (int j = 0; j < 4; ++j)
    tile[ty + j * 8][tx] = s[(long)(r0 + ty + j * 8) * 768 + c0 + tx];
  __syncthreads();
#pragma unroll
  for (int j = 0; j < 4; ++j)
    d[(long)(c0 + ty + j * 8) * 128 + r0 + tx] = tile[tx][ty + j * 8];
}

// Matching attention probs: logits f32 in, bf16 a out
__global__ __launch_bounds__(128) void match_softmax_k(const float* __restrict__ logits,
                                                       const float* __restrict__ umask,
                                                       ushort* __restrict__ abf) {
  const int bx = blockIdx.x;           // b*128 + t
  const int b = bx >> 7;
  const int s = threadIdx.x;
  __shared__ float red[128];
  const float* row = logits + (long)bx * 128;
  const float um = umask[b * 128 + s];
  const float v = tanhf(row[s] * um * um);
  red[s] = v; __syncthreads();
  for (int off = 64; off > 0; off >>= 1) { if (s < off) red[s] = fmaxf(red[s], red[s + off]); __syncthreads(); }
  const float m = red[0]; __syncthreads();
  const float e = expf(v - m);
  red[s] = e; __syncthreads();
  for (int off = 64; off > 0; off >>= 1) { if (s < off) red[s] += red[s + off]; __syncthreads(); }
  const float es = red[0]; __syncthreads();
  const float p = (e / es) * um;
  red[s] = p; __syncthreads();
  for (int off = 64; off > 0; off >>= 1) { if (s < off) red[s] += red[s + off]; __syncthreads(); }
  const float ps = red[0];
  abf[(long)bx * 128 + s] = f2bf(p / ps);
}

__global__ __launch_bounds__(256) void final_k(const float* __restrict__ hidden,
                                               const float* __restrict__ Ws,
                                               const float* __restrict__ bs,
                                               float* __restrict__ out) {
  __shared__ float wsl[256 * 6];
  const int tid = threadIdx.x;
#pragma unroll
  for (int j = 0; j < 6; ++j) wsl[tid * 6 + j] = Ws[tid * 6 + j];
  __syncthreads();
  const int wave = tid >> 6, lane = tid & 63;
  const int n = blockIdx.x * 4 + wave;
  const float4 hv = *(const float4*)&hidden[(long)n * 256 + lane * 4];
  const float hvv[4] = {hv.x, hv.y, hv.z, hv.w};
  float a[6];
#pragma unroll
  for (int c = 0; c < 6; ++c) a[c] = 0.f;
#pragma unroll
  for (int j = 0; j < 4; ++j)
#pragma unroll
    for (int c = 0; c < 6; ++c)
      a[c] = fmaf(hvv[j], wsl[(lane * 4 + j) * 6 + c], a[c]);
#pragma unroll
  for (int off = 32; off > 0; off >>= 1)
#pragma unroll
    for (int c = 0; c < 6; ++c)
      a[c] += __shfl_xor(a[c], off, 64);
  if (lane == 0) {
    float v[6], m = -1e30f;
#pragma unroll
    for (int c = 0; c < 6; ++c) { v[c] = a[c] + bs[c]; m = fmaxf(m, v[c]); }
    float sum = 0.f;
#pragma unroll
    for (int c = 0; c < 6; ++c) sum += expf(v[c] - m);
    const float lse = m + logf(sum);
#pragma unroll
    for (int c = 0; c < 6; ++c) out[(long)n * 6 + c] = v[c] - lse;
  }
}

// ---------------------------------------------------------------------------
// Orchestration
// ---------------------------------------------------------------------------
extern "C" void kernel_launch(void* const* d_in, const int* in_sizes, int n_in,
                              void* d_out, int out_size, void* d_ws, size_t ws_size,
                              hipStream_t stream) {
  const float* U        = (const float*)d_in[0];
  const float* umask    = (const float*)d_in[1];
  const float* Wih0     = (const float*)d_in[2];
  const float* Whh0     = (const float*)d_in[3];
  const float* b0       = (const float*)d_in[4];
  const float* Wih1     = (const float*)d_in[5];
  const float* Whh1     = (const float*)d_in[6];
  const float* b1       = (const float*)d_in[7];
  const float* W_scalar = (const float*)d_in[8];
  const float* basis    = (const float*)d_in[9];
  const float* comp     = (const float*)d_in[10];
  const float* W_root   = (const float*)d_in[11];
  const float* b_rgcn   = (const float*)d_in[12];
  const float* gc_W1    = (const float*)d_in[13];
  const float* gc_W2    = (const float*)d_in[14];
  const float* gc_b     = (const float*)d_in[15];
  const float* Wm       = (const float*)d_in[16];
  const float* bm       = (const float*)d_in[17];
  const float* Wl       = (const float*)d_in[18];
  const float* bl       = (const float*)d_in[19];
  const float* Wsw      = (const float*)d_in[20];
  const float* bsw      = (const float*)d_in[21];
  const int*   speakers = (const int*)d_in[22];

  float* ws = (float*)d_ws;
  // Regions (float offsets), lifetimes audited:
  float* gates   = ws + 0L;          // 16.78M f: gates0/1 -> xrelbf -> xtrbf
  float* feats   = ws + 16777216L;   //  4.19M f: wih0bf/wih1bf -> attbf
  float* xbuf    = ws + 20971520L;   //  4.19M f: ubf -> hagg -> emT
  float* feats0  = ws + 25165824L;   //  4.19M f: f0bf -> xemb [8192][768]
  float* scaleb  = ws + 29360128L;   //  1.05M f: scale -> logits -> hidden(lo)
  float* scoresb = ws + 30408704L;   //  1.05M f: wscT -> abf -> hidden(hi)
  float* wrelr   = ws + 31457280L;   //  1.05M f: wrel2t bf16
  float* hroot   = ws + 32505856L;   //  2.10M f: hroot f32
  uint*  wq      = (uint*)(ws + 34603008L);   // 262,144 dwords
  float* fsc     = ws + 34865152L;            // 4,096
  float* wTr     = ws + 34869248L;            // 524,288 f (transposed weights)

  ushort* ubf    = (ushort*)xbuf;
  ushort* wih0bf = (ushort*)feats;
  ushort* wih1bf = (ushort*)(feats + 1048576L);
  ushort* f0bf   = (ushort*)feats0;              // dead after gates L1 gemm
  ushort* xemb   = (ushort*)feats0;              // [8192][768]: x | gc-out
  ushort* wrel2t = (ushort*)wrelr;
  ushort* wroott = (ushort*)wTr;                 // 131,072 us (256 x 512)
  ushort* gcW12t = wroott + 131072L;             // 131,072 us (256 x 512 stacked)
  ushort* Wmt    = gcW12t + 131072L;             // 589,824 us
  ushort* Wlt    = Wmt + 589824L;                // 196,608 us
  ushort* wscT   = (ushort*)scoresb;             // 65,536 us (dead after scale gemm)

  ushort* hagg    = (ushort*)xbuf;               // [8192][512]: h | agg (ubf dead)
  ushort* emT     = (ushort*)xbuf;               // after gc gemm (hagg dead)
  ushort* xrelbf  = (ushort*)gates;
  ushort* xtrbf   = (ushort*)gates;
  ushort* abf     = (ushort*)scoresb;
  ushort* attbf   = (ushort*)feats;

  float*  logitsb = scaleb;
  float*  hiddenb = scaleb;

  // --- weight prep (4 dispatches) ---
  pack_whh_all_k<<<1024, 256, 0, stream>>>(Whh0, Whh1, wq, fsc);
  cvt_all_k<<<11264, 256, 0, stream>>>(U, ubf, Wih0, wih0bf, Wih1, wih1bf);
  tp_all_k<<<1088, 256, 0, stream>>>(W_root, wroott, gc_W1, gc_W2, gcW12t,
                                     Wm, Wmt, Wl, Wlt, W_scalar, wscT);
  wrel_k<<<512, 256, 0, stream>>>(basis, comp, wrel2t);

  // --- layer 0 ---
  gemm_bf16_nt<true, false, false, false><<<dim3(8, 64, 2), 256, 0, stream>>>(
      ubf, wih0bf, b0, gates, 8192, 1024, 1024, 1024L, 1024L,
      0L, 1048576L, 8388608L, 1024L);
  lstm4_k<<<128, 1024, 0, stream>>>(gates, wq, fsc, f0bf, 0, 512L);

  // --- layer 1 (writes x directly into xemb cols [0:512), b-major) ---
  gemm_bf16_nt<true, false, false, false><<<dim3(8, 64, 2), 256, 0, stream>>>(
      f0bf, wih1bf, b1, gates, 8192, 1024, 512, 512L, 1024L,
      0L, 524288L, 8388608L, 1024L);
  lstm4_k<<<128, 1024, 0, stream>>>(gates, wq + 131072, fsc + 2048, xemb, 1, 768L);

  // --- edge scale + RGCN ---
  gemm_bf16_nt<false, false, false, false><<<dim3(1, 64, 1), 256, 0, stream>>>(
      xemb, wscT, nullptr, scaleb, 8192, 128, 512, 768L, 128L, 0L, 0L, 0L, 0L);
  gemm_bf16_nt<true, false, false, false><<<dim3(2, 64, 1), 256, 0, stream>>>(
      xemb, wroott, b_rgcn, hroot, 8192, 256, 512, 768L, 256L, 0L, 0L, 0L, 0L);
  gemm_bf16_nt<false, false, false, true><<<dim3(16, 64, 1), 256, 0, stream>>>(
      xemb, wrel2t, nullptr, xrelbf, 8192, 2048, 512, 768L, 2048L, 0L, 0L, 0L, 0L);
  rgcn_fused_k<<<8192, 256, 0, stream>>>(scaleb, xrelbf, hroot, speakers, hagg);

  // --- GraphConv (merged: [h|agg] @ [W1;W2] + b -> xemb cols [512:768)) ---
  agg_k<<<8192, 256, 0, stream>>>(hagg);
  gemm_bf16_nt<true, false, false, true><<<dim3(2, 64, 1), 256, 0, stream>>>(
      hagg, gcW12t, gc_b, xemb + 512, 8192, 256, 512, 512L, 768L, 0L, 0L, 0L, 0L);

  // --- matching attention ---
  gemm_bf16_nt<true, false, false, true><<<dim3(6, 64, 1), 256, 0, stream>>>(
      xemb, Wmt, bm, xtrbf, 8192, 768, 768, 768L, 768L, 0L, 0L, 0L, 0L);
  emt_k<<<dim3(24, 4, 64), 256, 0, stream>>>(xemb, emT);
  gemm_bf16_nt<false, false, false, false><<<dim3(1, 1, 64), 256, 0, stream>>>(
      xtrbf, xemb, nullptr, logitsb, 128, 128, 768, 768L, 128L,
      98304L, 98304L, 16384L, 0L);
  match_softmax_k<<<8192, 128, 0, stream>>>(logitsb, umask, abf);
  gemm_bf16_nt<false, false, false, true><<<dim3(6, 1, 64), 256, 0, stream>>>(
      abf, emT, nullptr, attbf, 128, 768, 128, 128L, 768L,
      16384L, 98304L, 98304L, 0L);

  // --- classifier ---
  gemm_bf16_nt<true, false, true, false><<<dim3(2, 64, 1), 256, 0, stream>>>(
      attbf, Wlt, bl, hiddenb, 8192, 256, 768, 768L, 256L, 0L, 0L, 0L, 0L);
  final_k<<<2048, 256, 0, stream>>>(hiddenb, Wsw, bsw, (float*)d_out);
}

// Round 16
// 584.070 us; speedup vs baseline: 1.3283x; 1.0460x over previous
//
#include <hip/hip_runtime.h>
#include <cstdint>

// Model dims (fixed): L=128, B=64, DM=1024, H=256, F=512, HID=256, MEM=768,
// N=B*L=8192, NC=6, R=8, NB=30, WIN=10

typedef __attribute__((ext_vector_type(8))) short bf16x8;
typedef __attribute__((ext_vector_type(4))) float f32x4;

__device__ __forceinline__ void gload_lds16(const void* g, void* l) {
  __builtin_amdgcn_global_load_lds(
      (const __attribute__((address_space(1))) void*)g,
      (__attribute__((address_space(3))) void*)l, 16, 0, 0);
}

// ---------------------------------------------------------------------------
// bf16 NT MFMA GEMM (proven): 128x128x32 tile, 4 waves, global_load_lds.
// A row stride lda, C row stride ldc (B row stride == K). Batched via z.
// ---------------------------------------------------------------------------
template<bool HASBIAS, bool ACCUM, bool RELU, bool OUTBF>
__global__ __launch_bounds__(256) void gemm_bf16_nt(
    const ushort* __restrict__ A, const ushort* __restrict__ Bt,
    const float* __restrict__ bias, void* __restrict__ Cv,
    int M, int N, int K, long lda, long ldc,
    long sA, long sB, long sC, long sBias)
{
  const int bz = blockIdx.z;
  A += (long)bz * sA;
  Bt += (long)bz * sB;
  if (HASBIAS) bias += (long)bz * sBias;
  float*  Cf = OUTBF ? nullptr : ((float*)Cv + (long)bz * sC);
  ushort* Cb = OUTBF ? ((ushort*)Cv + (long)bz * sC) : nullptr;

  const int bn = blockIdx.x * 128, bm = blockIdx.y * 128;

  __shared__ ushort As[128][32];
  __shared__ ushort Bs[128][32];

  const int tid = threadIdx.x;
  const int wave = tid >> 6, lane = tid & 63;
  const int wm = (wave >> 1) * 64, wn = (wave & 1) * 64;
  const int fr = lane & 15;
  const int fk = (lane >> 4) * 8;

  f32x4 acc[4][4];
#pragma unroll
  for (int i = 0; i < 4; ++i)
#pragma unroll
    for (int j = 0; j < 4; ++j) acc[i][j] = (f32x4){0.f, 0.f, 0.f, 0.f};

  const int f0 = wave * 2 * 64 + lane;
  const int f1 = f0 + 64;
  const int r0 = f0 >> 2, c0 = (f0 & 3) * 8;
  const int r1 = f1 >> 2, c1 = (f1 & 3) * 8;
  ushort* As0 = (ushort*)As + wave * 2 * 512;
  ushort* As1 = As0 + 512;
  ushort* Bs0 = (ushort*)Bs + wave * 2 * 512;
  ushort* Bs1 = Bs0 + 512;

  for (int k0 = 0; k0 < K; k0 += 32) {
    gload_lds16(A + (long)(bm + r0) * lda + k0 + c0, As0);
    gload_lds16(A + (long)(bm + r1) * lda + k0 + c1, As1);
    gload_lds16(Bt + (long)(bn + r0) * K + k0 + c0, Bs0);
    gload_lds16(Bt + (long)(bn + r1) * K + k0 + c1, Bs1);
    __syncthreads();

    bf16x8 af[4], bfr[4];
#pragma unroll
    for (int f = 0; f < 4; ++f) {
      af[f]  = *(const bf16x8*)&As[wm + f * 16 + fr][fk];
      bfr[f] = *(const bf16x8*)&Bs[wn + f * 16 + fr][fk];
    }
#pragma unroll
    for (int mf = 0; mf < 4; ++mf)
#pragma unroll
      for (int nf = 0; nf < 4; ++nf)
        acc[mf][nf] = __builtin_amdgcn_mfma_f32_16x16x32_bf16(
            af[mf], bfr[nf], acc[mf][nf], 0, 0, 0);
    __syncthreads();
  }

  float bv[4];
#pragma unroll
  for (int nf = 0; nf < 4; ++nf)
    bv[nf] = HASBIAS ? bias[bn + wn + nf * 16 + fr] : 0.f;

  const int crow0 = (lane >> 4) * 4;
#pragma unroll
  for (int mf = 0; mf < 4; ++mf)
#pragma unroll
    for (int r = 0; r < 4; ++r) {
      const long roff = (long)(bm + wm + mf * 16 + crow0 + r) * ldc + bn + wn;
#pragma unroll
      for (int nf = 0; nf < 4; ++nf) {
        float v = acc[mf][nf][r] + bv[nf];
        if (OUTBF) {
          unsigned u = __float_as_uint(v);
          u += 0x7fffu + ((u >> 16) & 1u);
          Cb[roff + nf * 16 + fr] = (ushort)(u >> 16);
        } else {
          if (ACCUM) v += Cf[roff + nf * 16 + fr];
          if (RELU) v = fmaxf(v, 0.f);
          Cf[roff + nf * 16 + fr] = v;
        }
      }
    }
}

// ---------------------------------------------------------------------------
// helpers
// ---------------------------------------------------------------------------
__device__ __forceinline__ unsigned short f2bf(float f) {
  unsigned u = __float_as_uint(f);
  u += 0x7fffu + ((u >> 16) & 1u);
  return (unsigned short)(u >> 16);
}
__device__ __forceinline__ float bf2f(ushort v) {
  return __uint_as_float(((unsigned)v) << 16);
}
__device__ __forceinline__ float fast_sig(float x) {
  return __builtin_amdgcn_rcpf(1.f + __expf(-x));
}
__device__ __forceinline__ float fast_tanh(float x) {
  return 2.f * fast_sig(2.f * x) - 1.f;
}

__device__ __forceinline__ int sdot4_(uint a, uint b, int c) {
#if __has_builtin(__builtin_amdgcn_sdot4)
  return __builtin_amdgcn_sdot4((int)a, (int)b, c, false);
#else
  int r = c;
  r += ((int)(a << 24) >> 24) * ((int)(b << 24) >> 24);
  r += ((int)(a << 16) >> 24) * ((int)(b << 16) >> 24);
  r += ((int)(a << 8)  >> 24) * ((int)(b << 8)  >> 24);
  r += ((int)a >> 24)         * ((int)b >> 24);
  return r;
#endif
}

// Fused f32->bf16 conversions (U, Wih0, Wih1) + stacked scale|root bias build
__global__ __launch_bounds__(256) void cvt_all_k(
    const float* __restrict__ U, ushort* __restrict__ ubf,
    const float* __restrict__ W0, ushort* __restrict__ w0,
    const float* __restrict__ W1, ushort* __restrict__ w1,
    const float* __restrict__ b_rgcn, float* __restrict__ biasSW)
{
  const int bid = blockIdx.x;
  if (bid >= 11264) {
    const int idx = (bid - 11264) * 256 + threadIdx.x;
    if (idx < 384) biasSW[idx] = (idx < 128) ? 0.f : b_rgcn[idx - 128];
    return;
  }
  const float* src; ushort* dst; long base;
  if (bid < 8192)       { src = U;  dst = ubf; base = (long)bid * 1024; }
  else if (bid < 10240) { src = W0; dst = w0;  base = (long)(bid - 8192) * 1024; }
  else                  { src = W1; dst = w1;  base = (long)(bid - 10240) * 1024; }
  const long i = base + threadIdx.x * 4;
  float4 v = *(const float4*)(src + i);
  ushort4 o;
  o.x = f2bf(v.x); o.y = f2bf(v.y); o.z = f2bf(v.z); o.w = f2bf(v.w);
  *(ushort4*)(dst + i) = o;
}

// Fused transpose+bf16 for the weight matrices. Each job: dst[c*dstStride +
// dstOff + r] = src[r*C + c]. W_scalar|W_root stack rows into one 384x512;
// gc_W1/gc_W2 stack K into one 256x512.
__global__ __launch_bounds__(256) void tp_all_k(
    const float* __restrict__ s0, ushort* __restrict__ d0,   // W_root 512x256 -> rows 128..383
    const float* __restrict__ s1, const float* __restrict__ s2,
    ushort* __restrict__ d12,                                // gc stacked 256x512
    const float* __restrict__ s3, ushort* __restrict__ d3,   // Wm 768x768
    const float* __restrict__ s4, ushort* __restrict__ d4,   // Wl 768x256
    const float* __restrict__ s5, ushort* __restrict__ d5)   // W_scalar 512x128 -> rows 0..127
{
  __shared__ float tile[32][33];
  const int bid = blockIdx.x;
  const float* src; ushort* dst; int C, gx, local, dstStride, dstOff;
  if (bid < 128)       { src = s0; dst = d0;  C = 256; gx = 8;  local = bid;        dstStride = 512; dstOff = 0; }
  else if (bid < 192)  { src = s1; dst = d12; C = 256; gx = 8;  local = bid - 128;  dstStride = 512; dstOff = 0; }
  else if (bid < 256)  { src = s2; dst = d12; C = 256; gx = 8;  local = bid - 192;  dstStride = 512; dstOff = 256; }
  else if (bid < 832)  { src = s3; dst = d3;  C = 768; gx = 24; local = bid - 256;  dstStride = 768; dstOff = 0; }
  else if (bid < 1024) { src = s4; dst = d4;  C = 256; gx = 8;  local = bid - 832;  dstStride = 768; dstOff = 0; }
  else                 { src = s5; dst = d5;  C = 128; gx = 4;  local = bid - 1024; dstStride = 512; dstOff = 0; }
  const int c0 = (local % gx) * 32, r0 = (local / gx) * 32;
  const int tx = threadIdx.x & 31, ty = threadIdx.x >> 5;
#pragma unroll
  for (int j = 0; j < 4; ++j)
    tile[ty + j * 8][tx] = src[(long)(r0 + ty + j * 8) * C + c0 + tx];
  __syncthreads();
#pragma unroll
  for (int j = 0; j < 4; ++j)
    dst[(long)(c0 + ty + j * 8) * dstStride + dstOff + r0 + tx] = f2bf(tile[tx][ty + j * 8]);
}

// Fused Whh pack (both layers): (2,1024,256) f32 -> int8 dwords + scales
__global__ __launch_bounds__(256) void pack_whh_all_k(
    const float* __restrict__ Whh0, const float* __restrict__ Whh1,
    uint* __restrict__ Wq, float* __restrict__ fscale)
{
  const int wid = (blockIdx.x * 256 + threadIdx.x) >> 6;  // 0..4095
  const int lane = threadIdx.x & 63;
  const int l = wid >> 11;
  const int wid2 = wid & 2047;
  const int d = wid2 >> 10, gi = wid2 & 1023;
  const float* Whh = l ? Whh1 : Whh0;
  const float* row = Whh + ((long)d * 1024 + gi) * 256 + lane * 4;
  float v0 = row[0], v1 = row[1], v2 = row[2], v3 = row[3];
  float am = fmaxf(fmaxf(fabsf(v0), fabsf(v1)), fmaxf(fabsf(v2), fabsf(v3)));
#pragma unroll
  for (int off = 32; off > 0; off >>= 1) am = fmaxf(am, __shfl_xor(am, off, 64));
  am = fmaxf(am, 1e-12f);
  const float inv = 127.f / am;
  int q0 = __float2int_rn(v0 * inv), q1 = __float2int_rn(v1 * inv);
  int q2 = __float2int_rn(v2 * inv), q3 = __float2int_rn(v3 * inv);
  uint w = (uint)(q0 & 255) | ((uint)(q1 & 255) << 8) |
           ((uint)(q2 & 255) << 16) | ((uint)(q3 & 255) << 24);
  Wq[(long)l * 131072 + ((long)d * 64 + lane) * 1024 + gi] = w;
  if (lane == 0) fscale[l * 2048 + d * 1024 + gi] = am / 127.f;
}

// ---------------------------------------------------------------------------
// LSTM v4 (proven structure; gates now bf16): int8 weights streamed from L2,
// int8 h via LDS broadcast, sdot4; bf16 output with row stride ldo.
// ---------------------------------------------------------------------------
__global__ __launch_bounds__(1024) void lstm4_k(
    const ushort* __restrict__ Xg,   // (2, 8192, 1024) bf16 gate preacts
    const uint* __restrict__ Wq,
    const float* __restrict__ fscale,
    ushort* __restrict__ out,
    int bmajor, long ldo)
{
  const int bx = blockIdx.x;
  const int d = bx >> 6, b = bx & 63;
  const int tid = threadIdx.x;

  __shared__ uint hq[2][64];
  __shared__ float preactF[1024];

  uint w[64];
  const uint* wrow = Wq + (long)d * 65536 + tid;
#pragma unroll
  for (int k4 = 0; k4 < 64; ++k4) w[k4] = wrow[k4 * 1024];

  if (tid < 128) ((uint*)hq)[tid] = 0u;

  const float fsc = fscale[d * 1024 + tid] * (1.0f / 127.0f);
  const ushort* Xd = Xg + (long)d * 8192 * 1024;

  float c = 0.f;
  float x0 = 0.f, x1 = 0.f, x2 = 0.f, x3 = 0.f;
  if (tid < 256) {
    const ushort* xr = Xd + ((long)((d ? 127 : 0) * 64 + b)) * 1024;
    x0 = bf2f(xr[tid]); x1 = bf2f(xr[tid + 256]);
    x2 = bf2f(xr[tid + 512]); x3 = bf2f(xr[tid + 768]);
  }
  __syncthreads();

  int cur = 0;
  for (int step = 0; step < 128; ++step) {
    const int t = d ? 127 - step : step;

    float n0 = 0.f, n1 = 0.f, n2 = 0.f, n3 = 0.f;
    if (tid < 256 && step + 1 < 128) {
      const ushort* xr = Xd + ((long)((d ? 126 - step : step + 1) * 64 + b)) * 1024;
      n0 = bf2f(xr[tid]); n1 = bf2f(xr[tid + 256]);
      n2 = bf2f(xr[tid + 512]); n3 = bf2f(xr[tid + 768]);
    }

    int acc = 0;
    const uint4* hrow = (const uint4*)hq[cur];
#pragma unroll
    for (int k16 = 0; k16 < 16; ++k16) {
      uint4 h4 = hrow[k16];
      acc = sdot4_(w[k16 * 4 + 0], h4.x, acc);
      acc = sdot4_(w[k16 * 4 + 1], h4.y, acc);
      acc = sdot4_(w[k16 * 4 + 2], h4.z, acc);
      acc = sdot4_(w[k16 * 4 + 3], h4.w, acc);
    }
    preactF[tid] = (float)acc * fsc;
    __syncthreads();

    if (tid < 256) {
      float p0 = x0 + preactF[tid];
      float p1 = x1 + preactF[tid + 256];
      float p2 = x2 + preactF[tid + 512];
      float p3 = x3 + preactF[tid + 768];
      const float ig = fast_sig(p0), fg = fast_sig(p1);
      const float gg = fast_tanh(p2), og = fast_sig(p3);
      c = fg * c + ig * gg;
      const float h = og * fast_tanh(c);
      const long row = bmajor ? ((long)b * 128 + t) : ((long)t * 64 + b);
      out[row * ldo + (d << 8) + tid] = f2bf(h);
      ((char*)hq[cur ^ 1])[tid] = (char)__float2int_rn(h * 127.f);
      x0 = n0; x1 = n1; x2 = n2; x3 = n3;
    }
    __syncthreads();
    cur ^= 1;
  }
}

// W_rel basis combination -> bf16 transposed (N=r*256+o rows, K=f cols)
__global__ __launch_bounds__(256) void wrel_k(const float* __restrict__ basis,
                                              const float* __restrict__ comp,
                                              ushort* __restrict__ wrel2t) {
  const int f = blockIdx.x;     // 0..511
  const int o = threadIdx.x;    // 0..255
  __shared__ float cs[240];
  if (o < 240) cs[o] = comp[o];
  __syncthreads();
  float acc[8];
#pragma unroll
  for (int r = 0; r < 8; ++r) acc[r] = 0.f;
  for (int bb = 0; bb < 30; ++bb) {
    const float v = basis[((long)bb * 512 + f) * 256 + o];
#pragma unroll
    for (int r = 0; r < 8; ++r) acc[r] = fmaf(cs[r * 30 + bb], v, acc[r]);
  }
#pragma unroll
  for (int r = 0; r < 8; ++r)
    wrel2t[((long)(r * 256 + o)) * 512 + f] = f2bf(acc[r]);
}

// ---------------------------------------------------------------------------
// RGCN gather FUSED with edge-attention softmax. scaleM is the merged
// [8192][384] output: cols [0:128) = scale (for softmax over sources),
// cols [128:384) = hroot. Writes the h half of the [8192][512] {h|agg}.
// ---------------------------------------------------------------------------
__global__ __launch_bounds__(256) void rgcn_fused_k(
    const float* __restrict__ scaleM, const ushort* __restrict__ xrel,
    const int* __restrict__ spk, ushort* __restrict__ hagg)
{
  const int n = blockIdx.x;
  const int b = n >> 7, t = n & 127;
  const int o = threadIdx.x;
  const int lo = max(t - 10, 0), hi = min(t + 10, 127);
  const int cnt = hi - lo + 1;

  __shared__ float sc[128], red[128];
  __shared__ int spks[21];
  __shared__ int spkt_s;

  if (o < 128) {
    const float v = scaleM[((long)(b * 128 + o)) * 384 + t];
    sc[o] = v; red[o] = v;
  }
  if (o == 0) spkt_s = spk[t * 64 + b];
  if (o >= 128 && o - 128 < cnt) spks[o - 128] = spk[(lo + o - 128) * 64 + b];
  __syncthreads();
  for (int off = 64; off > 0; off >>= 1) {
    if (o < off) red[o] = fmaxf(red[o], red[o + off]);
    __syncthreads();
  }
  const float m = red[0];
  __syncthreads();
  if (o < 128) {
    const float e = expf(sc[o] - m);
    sc[o] = e;
    const int dd = o - t;
    const bool inwin = (dd <= 10) && (dd >= -10);
    red[o] = e * (inwin ? 1.0f : 1e-10f);
  }
  __syncthreads();
  for (int off = 64; off > 0; off >>= 1) {
    if (o < off) red[o] += red[o + off];
    __syncthreads();
  }
  const float inv_msum = 1.0f / red[0];
  __syncthreads();

  const int spkt = spkt_s;
  float acc = scaleM[(long)n * 384 + 128 + o];
  for (int q = 0; q < cnt; ++q) {
    const int s = lo + q;
    const float wv = sc[s] * inv_msum;
    const int et = spkt * 4 + spks[q] * 2 + ((t < s) ? 0 : 1);
    acc = fmaf(bf2f(xrel[(((long)(b * 128 + s)) * 8 + et) * 256 + o]), wv, acc);
  }
  hagg[(long)n * 512 + o] = f2bf(acc);
}

// GraphConv neighbor aggregation: reads h half, writes agg half (cols 256+)
__global__ __launch_bounds__(256) void agg_k(ushort* __restrict__ hagg) {
  const int n = blockIdx.x;
  const int b = n >> 7, t = n & 127;
  const int o = threadIdx.x;
  const int lo = max(t - 10, 0), hi = min(t + 10, 127);
  float acc = 0.f;
  for (int s = lo; s <= hi; ++s) acc += bf2f(hagg[((long)(b * 128 + s)) * 512 + o]);
  hagg[(long)n * 512 + 256 + o] = f2bf(acc);
}

// Batched ushort transpose: dst[b](C x R) = src[b](R x C)^T, R=128, C=768.
__global__ __launch_bounds__(256) void emt_k(const ushort* __restrict__ src,
                                             ushort* __restrict__ dst) {
  __shared__ ushort tile[32][33];
  const int c0 = blockIdx.x * 32;
  const int r0 = blockIdx.y * 32;
  const int b = blockIdx.z;
  const ushort* s = src + (long)b * 98304;
  ushort* d = dst + (long)b * 98304;
  const int tx = threadIdx.x & 31, ty = threadIdx.x >> 5;
#pragma unroll
  for (int j = 0; j < 4; ++j)
    tile[ty + j * 8][tx] = s[(long)(r0 + ty + j * 8) * 768 + c0 + tx];
  __syncthreads();
#pragma unroll
  for (int j = 0; j < 4; ++j)
    d[(long)(c0 + ty + j * 8) * 128 + r0 + tx] = tile[tx][ty + j * 8];
}

// Matching attention probs: logits f32 in, bf16 a out
__global__ __launch_bounds__(128) void match_softmax_k(const float* __restrict__ logits,
                                                       const float* __restrict__ umask,
                                                       ushort* __restrict__ abf) {
  const int bx = blockIdx.x;           // b*128 + t
  const int b = bx >> 7;
  const int s = threadIdx.x;
  __shared__ float red[128];
  const float* row = logits + (long)bx * 128;
  const float um = umask[b * 128 + s];
  const float v = tanhf(row[s] * um * um);
  red[s] = v; __syncthreads();
  for (int off = 64; off > 0; off >>= 1) { if (s < off) red[s] = fmaxf(red[s], red[s + off]); __syncthreads(); }
  const float m = red[0]; __syncthreads();
  const float e = expf(v - m);
  red[s] = e; __syncthreads();
  for (int off = 64; off > 0; off >>= 1) { if (s < off) red[s] += red[s + off]; __syncthreads(); }
  const float es = red[0]; __syncthreads();
  const float p = (e / es) * um;
  red[s] = p; __syncthreads();
  for (int off = 64; off > 0; off >>= 1) { if (s < off) red[s] += red[s + off]; __syncthreads(); }
  const float ps = red[0];
  abf[(long)bx * 128 + s] = f2bf(p / ps);
}

__global__ __launch_bounds__(256) void final_k(const float* __restrict__ hidden,
                                               const float* __restrict__ Ws,
                                               const float* __restrict__ bs,
                                               float* __restrict__ out) {
  __shared__ float wsl[256 * 6];
  const int tid = threadIdx.x;
#pragma unroll
  for (int j = 0; j < 6; ++j) wsl[tid * 6 + j] = Ws[tid * 6 + j];
  __syncthreads();
  const int wave = tid >> 6, lane = tid & 63;
  const int n = blockIdx.x * 4 + wave;
  const float4 hv = *(const float4*)&hidden[(long)n * 256 + lane * 4];
  const float hvv[4] = {hv.x, hv.y, hv.z, hv.w};
  float a[6];
#pragma unroll
  for (int c = 0; c < 6; ++c) a[c] = 0.f;
#pragma unroll
  for (int j = 0; j < 4; ++j)
#pragma unroll
    for (int c = 0; c < 6; ++c)
      a[c] = fmaf(hvv[j], wsl[(lane * 4 + j) * 6 + c], a[c]);
#pragma unroll
  for (int off = 32; off > 0; off >>= 1)
#pragma unroll
    for (int c = 0; c < 6; ++c)
      a[c] += __shfl_xor(a[c], off, 64);
  if (lane == 0) {
    float v[6], m = -1e30f;
#pragma unroll
    for (int c = 0; c < 6; ++c) { v[c] = a[c] + bs[c]; m = fmaxf(m, v[c]); }
    float sum = 0.f;
#pragma unroll
    for (int c = 0; c < 6; ++c) sum += expf(v[c] - m);
    const float lse = m + logf(sum);
#pragma unroll
    for (int c = 0; c < 6; ++c) out[(long)n * 6 + c] = v[c] - lse;
  }
}

// ---------------------------------------------------------------------------
// Orchestration
// ---------------------------------------------------------------------------
extern "C" void kernel_launch(void* const* d_in, const int* in_sizes, int n_in,
                              void* d_out, int out_size, void* d_ws, size_t ws_size,
                              hipStream_t stream) {
  const float* U        = (const float*)d_in[0];
  const float* umask    = (const float*)d_in[1];
  const float* Wih0     = (const float*)d_in[2];
  const float* Whh0     = (const float*)d_in[3];
  const float* b0       = (const float*)d_in[4];
  const float* Wih1     = (const float*)d_in[5];
  const float* Whh1     = (const float*)d_in[6];
  const float* b1       = (const float*)d_in[7];
  const float* W_scalar = (const float*)d_in[8];
  const float* basis    = (const float*)d_in[9];
  const float* comp     = (const float*)d_in[10];
  const float* W_root   = (const float*)d_in[11];
  const float* b_rgcn   = (const float*)d_in[12];
  const float* gc_W1    = (const float*)d_in[13];
  const float* gc_W2    = (const float*)d_in[14];
  const float* gc_b     = (const float*)d_in[15];
  const float* Wm       = (const float*)d_in[16];
  const float* bm       = (const float*)d_in[17];
  const float* Wl       = (const float*)d_in[18];
  const float* bl       = (const float*)d_in[19];
  const float* Wsw      = (const float*)d_in[20];
  const float* bsw      = (const float*)d_in[21];
  const int*   speakers = (const int*)d_in[22];

  float* ws = (float*)d_ws;
  // Regions (float offsets), lifetimes audited:
  float* gates   = ws + 0L;          // 16.78M f: gatesbf(8.39M) | scaleM(8.39..11.54M) -> xrelbf -> xtrbf
  float* feats   = ws + 16777216L;   //  4.19M f: wih0bf/wih1bf -> attbf
  float* xbuf    = ws + 20971520L;   //  4.19M f: ubf -> hagg -> emT
  float* feats0  = ws + 25165824L;   //  4.19M f: f0bf -> xemb [8192][768]
  float* scaleb  = ws + 29360128L;   //  1.05M f: logits -> hidden(lo)
  float* scoresb = ws + 30408704L;   //  1.05M f: abf -> hidden(hi)
  float* wrelr   = ws + 31457280L;   //  1.05M f: wrel2t bf16
  uint*  wq      = (uint*)(ws + 34603008L);   // 262,144 dwords
  float* fsc     = ws + 34865152L;            // 4,096
  float* wTr     = ws + 34869248L;            // 557,056 f (transposed weights)
  float* biasSW  = ws + 35426304L;            // 384 f (stacked scale|root bias)

  ushort* ubf    = (ushort*)xbuf;
  ushort* wih0bf = (ushort*)feats;
  ushort* wih1bf = (ushort*)(feats + 1048576L);
  ushort* f0bf   = (ushort*)feats0;              // dead after gates L1 gemm
  ushort* xemb   = (ushort*)feats0;              // [8192][768]: x | gc-out
  ushort* wrel2t = (ushort*)wrelr;
  ushort* wswr   = (ushort*)wTr;                 // 196,608 us (384 x 512 stacked)
  ushort* gcW12t = wswr + 196608L;               // 131,072 us (256 x 512 stacked)
  ushort* Wmt    = gcW12t + 131072L;             // 589,824 us
  ushort* Wlt    = Wmt + 589824L;                // 196,608 us

  ushort* gatesbf = (ushort*)gates;              // (2,8192,1024) bf16 gate preacts
  float*  scaleM  = gates + 8388608L;            // [8192][384] f32 scale|hroot
  ushort* hagg    = (ushort*)xbuf;               // [8192][512]: h | agg (ubf dead)
  ushort* emT     = (ushort*)xbuf;               // after gc gemm (hagg dead)
  ushort* xrelbf  = (ushort*)gates;              // [0..8.39M f)
  ushort* xtrbf   = (ushort*)gates;              // after rgcn (xrelbf/scaleM dead)
  ushort* abf     = (ushort*)scoresb;
  ushort* attbf   = (ushort*)feats;

  float*  logitsb = scaleb;
  float*  hiddenb = scaleb;

  // --- weight prep (4 dispatches) ---
  pack_whh_all_k<<<1024, 256, 0, stream>>>(Whh0, Whh1, wq, fsc);
  cvt_all_k<<<11266, 256, 0, stream>>>(U, ubf, Wih0, wih0bf, Wih1, wih1bf,
                                       b_rgcn, biasSW);
  tp_all_k<<<1088, 256, 0, stream>>>(W_root, wswr + 65536L, gc_W1, gc_W2, gcW12t,
                                     Wm, Wmt, Wl, Wlt, W_scalar, wswr);
  wrel_k<<<512, 256, 0, stream>>>(basis, comp, wrel2t);

  // --- layer 0 (bf16 gates) ---
  gemm_bf16_nt<true, false, false, true><<<dim3(8, 64, 2), 256, 0, stream>>>(
      ubf, wih0bf, b0, gatesbf, 8192, 1024, 1024, 1024L, 1024L,
      0L, 1048576L, 8388608L, 1024L);
  lstm4_k<<<128, 1024, 0, stream>>>(gatesbf, wq, fsc, f0bf, 0, 512L);

  // --- layer 1 (bf16 gates; writes x into xemb cols [0:512), b-major) ---
  gemm_bf16_nt<true, false, false, true><<<dim3(8, 64, 2), 256, 0, stream>>>(
      f0bf, wih1bf, b1, gatesbf, 8192, 1024, 512, 512L, 1024L,
      0L, 524288L, 8388608L, 1024L);
  lstm4_k<<<128, 1024, 0, stream>>>(gatesbf, wq + 131072, fsc + 2048, xemb, 1, 768L);

  // --- merged edge-scale | W_root GEMM + xrel + fused RGCN ---
  gemm_bf16_nt<true, false, false, false><<<dim3(3, 64, 1), 256, 0, stream>>>(
      xemb, wswr, biasSW, scaleM, 8192, 384, 512, 768L, 384L, 0L, 0L, 0L, 0L);
  gemm_bf16_nt<false, false, false, true><<<dim3(16, 64, 1), 256, 0, stream>>>(
      xemb, wrel2t, nullptr, xrelbf, 8192, 2048, 512, 768L, 2048L, 0L, 0L, 0L, 0L);
  rgcn_fused_k<<<8192, 256, 0, stream>>>(scaleM, xrelbf, speakers, hagg);

  // --- GraphConv (merged: [h|agg] @ [W1;W2] + b -> xemb cols [512:768)) ---
  agg_k<<<8192, 256, 0, stream>>>(hagg);
  gemm_bf16_nt<true, false, false, true><<<dim3(2, 64, 1), 256, 0, stream>>>(
      hagg, gcW12t, gc_b, xemb + 512, 8192, 256, 512, 512L, 768L, 0L, 0L, 0L, 0L);

  // --- matching attention ---
  gemm_bf16_nt<true, false, false, true><<<dim3(6, 64, 1), 256, 0, stream>>>(
      xemb, Wmt, bm, xtrbf, 8192, 768, 768, 768L, 768L, 0L, 0L, 0L, 0L);
  emt_k<<<dim3(24, 4, 64), 256, 0, stream>>>(xemb, emT);
  gemm_bf16_nt<false, false, false, false><<<dim3(1, 1, 64), 256, 0, stream>>>(
      xtrbf, xemb, nullptr, logitsb, 128, 128, 768, 768L, 128L,
      98304L, 98304L, 16384L, 0L);
  match_softmax_k<<<8192, 128, 0, stream>>>(logitsb, umask, abf);
  gemm_bf16_nt<false, false, false, true><<<dim3(6, 1, 64), 256, 0, stream>>>(
      abf, emT, nullptr, attbf, 128, 768, 128, 128L, 768L,
      16384L, 98304L, 98304L, 0L);

  // --- classifier ---
  gemm_bf16_nt<true, false, true, false><<<dim3(2, 64, 1), 256, 0, stream>>>(
      attbf, Wlt, bl, hiddenb, 8192, 256, 768, 768L, 256L, 0L, 0L, 0L, 0L);
  final_k<<<2048, 256, 0, stream>>>(hiddenb, Wsw, bsw, (float*)d_out);
}